// Round 5
// baseline (1202.122 us; speedup 1.0000x reference)
//
#include <hip/hip_runtime.h>

// MoE: x[8,4096,512]f32, assign[8,4096,2]i32, W1[8,512,2048], b1[8,2048],
//      W2[8,2048,512], b2[8,512] -> out[8,4096,512]f32
// v5: counted-vmcnt ring pipeline (8x16K slots, 3-phase lookahead), HC=128,
//     raw s_barrier + sched_barrier pins, H in LDS, bf16 MFMA 16x16x32.

#define NTOK 32768
#define DIM  512
#define HID  2048
#define NE   8
#define TM   128
#define NCH  16          // hidden chunks of 128
#define SLOT 16384
#define HOFF 131072      // 8 slots * 16K
#define LDS_BYTES 163840
#define MAXTILE 256      // worst-case coverage; extras early-exit

typedef __attribute__((ext_vector_type(8))) short short8;
typedef __attribute__((ext_vector_type(4))) float f32x4;
typedef __attribute__((ext_vector_type(4))) unsigned short us4;
typedef unsigned short ushort_t;

__device__ __forceinline__ unsigned short f2bf(float f) {
  union { float f; unsigned u; } v; v.f = f;
  unsigned r = v.u + 0x7FFFu + ((v.u >> 16) & 1u);  // RNE
  return (unsigned short)(r >> 16);
}

__device__ __forceinline__ void g2l16(const void* g, void* l) {
  __builtin_amdgcn_global_load_lds(
      (const __attribute__((address_space(1))) void*)g,
      (__attribute__((address_space(3))) void*)l, 16, 0, 0);
}
__device__ __forceinline__ void g2l16_nt(const void* g, void* l) {
  __builtin_amdgcn_global_load_lds(
      (const __attribute__((address_space(1))) void*)g,
      (__attribute__((address_space(3))) void*)l, 16, 0, 2);
}

// ---------------- routing ----------------
__global__ void moe_route(const int* __restrict__ assign, int* __restrict__ cnt,
                          int* __restrict__ lists) {
  int t = blockIdx.x * blockDim.x + threadIdx.x;
  if (t >= NTOK) return;
  int a0 = assign[2 * t + 0];
  int a1 = assign[2 * t + 1];
  if (a0 == a1) {
    int p = atomicAdd(&cnt[a0], 1);
    lists[a0 * NTOK + p] = t | 0x10000;  // weight 1.0
  } else {
    int p0 = atomicAdd(&cnt[a0], 1);
    lists[a0 * NTOK + p0] = t;           // weight 0.5
    int p1 = atomicAdd(&cnt[a1], 1);
    lists[a1 * NTOK + p1] = t;
  }
}

// ---------------- converters ----------------
__global__ __launch_bounds__(256) void cvt_x(const f32x4* __restrict__ x,
                                             us4* __restrict__ xb) {
  int i = blockIdx.x * 256 + threadIdx.x;
  f32x4 v = __builtin_nontemporal_load(&x[i]);
  us4 p;
  p.x = f2bf(v.x); p.y = f2bf(v.y); p.z = f2bf(v.z); p.w = f2bf(v.w);
  xb[i] = p;
}

// src: [E][R][C] fp32 -> dst: [E][C][R] bf16 (transpose + convert)
__global__ __launch_bounds__(256) void transp_cvt(const float* __restrict__ src,
                                                  ushort_t* __restrict__ dst,
                                                  int R, int C) {
  __shared__ float tile[64][68];
  const int e = blockIdx.z;
  const int rb = blockIdx.y * 64, cb = blockIdx.x * 64;
  const int t = threadIdx.x;
  {
    const int tr = t >> 2, tc = (t & 3) * 16;
    const f32x4* s = (const f32x4*)(src + ((size_t)e * R + rb + tr) * C + cb + tc);
    f32x4 v0 = __builtin_nontemporal_load(s + 0);
    f32x4 v1 = __builtin_nontemporal_load(s + 1);
    f32x4 v2 = __builtin_nontemporal_load(s + 2);
    f32x4 v3 = __builtin_nontemporal_load(s + 3);
    *(f32x4*)&tile[tr][tc + 0]  = v0;
    *(f32x4*)&tile[tr][tc + 4]  = v1;
    *(f32x4*)&tile[tr][tc + 8]  = v2;
    *(f32x4*)&tile[tr][tc + 12] = v3;
  }
  __syncthreads();
  {
    const int n = t >> 2, ks = (t & 3) * 16;
    short8 o0, o1;
#pragma unroll
    for (int j = 0; j < 8; ++j) o0[j] = (short)f2bf(tile[ks + j][n]);
#pragma unroll
    for (int j = 0; j < 8; ++j) o1[j] = (short)f2bf(tile[ks + 8 + j][n]);
    ushort_t* d = dst + ((size_t)e * C + cb + n) * R + rb + ks;
    *(short8*)(d) = o0;
    *(short8*)(d + 8) = o1;
  }
}

// ---------------- fused expert GEMM, ring-pipelined ----------------
__global__ __launch_bounds__(512, 1) void moe_gemm(
    const ushort_t* __restrict__ Xb, const ushort_t* __restrict__ W1b,
    const float* __restrict__ b1, const ushort_t* __restrict__ W2b,
    const float* __restrict__ b2, const int* __restrict__ cnt,
    const int* __restrict__ lists, float* __restrict__ out) {
  extern __shared__ char smem[];

  const int id = blockIdx.x;
  const int e = id & 7;          // expert == XCD (round-robin dispatch)
  const int tile = id >> 3;
  const int n_e = cnt[e];
  const int t0 = tile * TM;
  if (t0 >= n_e) return;

  const int tid = threadIdx.x;
  const int wid = tid >> 6;
  const int lane = tid & 63;
  const int lr = lane & 15, lg = lane >> 4;
  const int wm = wid >> 2;  // 0..1  (m half)
  const int wn = wid & 3;   // 0..3  (n quarter)

  // ---- staging geometry ----
  const int srow = tid >> 3;                        // 0..63
  const int sxor8 = ((tid & 7) ^ (srow & 7)) * 8;   // element offset (swizzled src)
  int tokA = 0, tokB = 0;
  {
    int i0 = t0 + srow, i1 = t0 + 64 + srow;
    if (i0 < n_e) tokA = lists[e * NTOK + i0] & 0xFFFF;
    if (i1 < n_e) tokB = lists[e * NTOK + i1] & 0xFFFF;
  }
  const ushort_t* gX0 = Xb + (size_t)tokA * DIM + sxor8;
  const ushort_t* gX1 = Xb + (size_t)tokB * DIM + sxor8;
  const ushort_t* gW1 = W1b + ((size_t)e * HID + srow) * DIM + sxor8;
  const ushort_t* gW2 = W2b + ((size_t)e * DIM + srow) * HID + sxor8;

  // b1 for chunk 0 (retired before pipeline waits matter; never counted)
  float b1a = b1[e * HID + wn * 32 + lr];
  float b1b = b1[e * HID + wn * 32 + 16 + lr];

  auto stX = [&](int p, int s) {
    char* d = smem + s * SLOT + tid * 16;
    g2l16_nt(gX0 + p * 64, d);
    g2l16_nt(gX1 + p * 64, d + 8192);
  };
  auto stW1 = [&](int c, int p, int s) {
    char* d = smem + s * SLOT + tid * 16;
    const ushort_t* g = gW1 + (size_t)(c * 128) * DIM + p * 64;
    g2l16(g, d);
    g2l16(g + (size_t)64 * DIM, d + 8192);
  };
  auto stV = [&](int c, int nq, int kq, int s) {
    char* d = smem + s * SLOT + tid * 16;
    const ushort_t* g = gW2 + (size_t)(nq * 128) * HID + c * 128 + kq * 64;
    g2l16(g, d);
    g2l16(g + (size_t)64 * HID, d + 8192);
  };

  f32x4 acc2[4][8];
#pragma unroll
  for (int i = 0; i < 4; ++i)
#pragma unroll
    for (int j = 0; j < 8; ++j) acc2[i][j] = f32x4{0.f, 0.f, 0.f, 0.f};

  // ---- prologue: stream slots 0..5 (X0,W0,X1,W1,X2,W2 of chunk 0) ----
  stX(0, 0); stW1(0, 0, 1); stX(1, 2); stW1(0, 1, 3); stX(2, 4); stW1(0, 2, 5);
  __builtin_amdgcn_sched_barrier(0);

  for (int c = 0; c < NCH; ++c) {
    const int cn = (c + 1) & 15;   // wrap: last chunk prefetches dead-but-valid data
    float nb1a = 0.f, nb1b = 0.f;

    f32x4 acc1[4][2];
#pragma unroll
    for (int i = 0; i < 4; ++i) {
      acc1[i][0] = f32x4{0.f, 0.f, 0.f, 0.f};
      acc1[i][1] = f32x4{0.f, 0.f, 0.f, 0.f};
    }

    // ================= G1: acc1 += X @ W1 chunk (8 phases) =================
#pragma unroll
    for (int p = 0; p < 8; ++p) {
      if (p == 0)      { stX(3, 6); stW1(c, 3, 7); }
      else if (p == 1) { stX(4, 0); stW1(c, 4, 1); }
      else if (p == 2) { stX(5, 2); stW1(c, 5, 3); }
      else if (p == 3) { stX(6, 4); stW1(c, 6, 5); }
      else if (p == 4) { stX(7, 6); stW1(c, 7, 7); }
      else if (p == 5) { stV(c, 0, 0, 0); stV(c, 0, 1, 1); }
      else if (p == 6) { stV(c, 1, 0, 2); stV(c, 1, 1, 3); }
      else             { stV(c, 2, 0, 4); stV(c, 2, 1, 5); }
      __builtin_amdgcn_sched_barrier(0);
      asm volatile("s_waitcnt vmcnt(12)" ::: "memory");
      __builtin_amdgcn_sched_barrier(0);
      __builtin_amdgcn_s_barrier();
      __builtin_amdgcn_sched_barrier(0);

      const int sX = (2 * p) & 7, sW = (2 * p + 1) & 7;
#pragma unroll
      for (int kf = 0; kf < 2; ++kf) {
        short8 a[4], b[2];
#pragma unroll
        for (int mf = 0; mf < 4; ++mf) {
          int m = wm * 64 + mf * 16 + lr;
          a[mf] = *(const short8*)(smem + sX * SLOT + m * 128 +
                                   (((kf * 4 + lg) ^ (m & 7)) << 4));
        }
#pragma unroll
        for (int nf = 0; nf < 2; ++nf) {
          int n = wn * 32 + nf * 16 + lr;
          b[nf] = *(const short8*)(smem + sW * SLOT + n * 128 +
                                   (((kf * 4 + lg) ^ (n & 7)) << 4));
        }
        __builtin_amdgcn_s_setprio(1);
#pragma unroll
        for (int mf = 0; mf < 4; ++mf)
#pragma unroll
          for (int nf = 0; nf < 2; ++nf)
            acc1[mf][nf] = __builtin_amdgcn_mfma_f32_16x16x32_bf16(
                a[mf], b[nf], acc1[mf][nf], 0, 0, 0);
        __builtin_amdgcn_s_setprio(0);
      }
      if (p == 7) {  // bias + relu -> H (swizzled bf16, [128 m][128 hid])
#pragma unroll
        for (int mf = 0; mf < 4; ++mf)
#pragma unroll
          for (int nf = 0; nf < 2; ++nf)
#pragma unroll
            for (int r = 0; r < 4; ++r) {
              int m = wm * 64 + mf * 16 + lg * 4 + r;
              int hc = wn * 32 + nf * 16 + lr;
              float hv = fmaxf(acc1[mf][nf][r] + (nf ? b1b : b1a), 0.0f);
              *(ushort_t*)(smem + HOFF + m * 256 +
                           ((((hc >> 3) ^ (m & 7)) << 4)) + (hc & 7) * 2) =
                  f2bf(hv);
            }
        __builtin_amdgcn_sched_barrier(0);
        asm volatile("s_waitcnt lgkmcnt(0)" ::: "memory");
      }
      __builtin_amdgcn_sched_barrier(0);
      __builtin_amdgcn_s_barrier();
      __builtin_amdgcn_sched_barrier(0);
    }

    // ================= G2: acc2 += H @ W2 chunk (8 phases) =================
#pragma unroll
    for (int q = 0; q < 8; ++q) {
      if (q == 0) {
        stV(c, 3, 0, 6); stV(c, 3, 1, 7);
        int bi = (c < 15 ? c + 1 : 15);
        nb1a = b1[e * HID + bi * 128 + wn * 32 + lr];
        nb1b = b1[e * HID + bi * 128 + wn * 32 + 16 + lr];
      }
      else if (q == 1) stX(0, 0);          // next chunk stream 24..29
      else if (q == 2) stW1(cn, 0, 1);
      else if (q == 3) stX(1, 2);
      else if (q == 4) stW1(cn, 1, 3);
      else if (q == 5) stX(2, 4);
      else if (q == 6) stW1(cn, 2, 5);
      __builtin_amdgcn_sched_barrier(0);
      if (q < 7) asm volatile("s_waitcnt vmcnt(14)" ::: "memory");
      else       asm volatile("s_waitcnt vmcnt(12)" ::: "memory");
      __builtin_amdgcn_sched_barrier(0);
      __builtin_amdgcn_s_barrier();
      __builtin_amdgcn_sched_barrier(0);

      const int nq = q >> 1, kq = q & 1;
#pragma unroll
      for (int kf = 0; kf < 2; ++kf) {
        short8 a[4], b[2];
#pragma unroll
        for (int mf = 0; mf < 4; ++mf) {
          int m = wm * 64 + mf * 16 + lr;
          a[mf] = *(const short8*)(smem + HOFF + m * 256 +
                                   (((kq * 8 + kf * 4 + lg) ^ (m & 7)) << 4));
        }
#pragma unroll
        for (int nf = 0; nf < 2; ++nf) {
          int n = wn * 32 + nf * 16 + lr;
          b[nf] = *(const short8*)(smem + q * SLOT + n * 128 +
                                   (((kf * 4 + lg) ^ (n & 7)) << 4));
        }
        __builtin_amdgcn_s_setprio(1);
#pragma unroll
        for (int mf = 0; mf < 4; ++mf)
#pragma unroll
          for (int nf = 0; nf < 2; ++nf)
            acc2[mf][nq * 2 + nf] = __builtin_amdgcn_mfma_f32_16x16x32_bf16(
                a[mf], b[nf], acc2[mf][nq * 2 + nf], 0, 0, 0);
        __builtin_amdgcn_s_setprio(0);
      }
      __builtin_amdgcn_sched_barrier(0);
      __builtin_amdgcn_s_barrier();
      __builtin_amdgcn_sched_barrier(0);
    }
    b1a = nb1a; b1b = nb1b;
  }
  asm volatile("" :: "v"(b1a), "v"(b1b));  // keep tail prefetch alive (uniform counts)

  // ---- epilogue: out[tok] += (acc2 + b2) * w ----
  float b2v[8];
#pragma unroll
  for (int j = 0; j < 8; ++j)
    b2v[j] = b2[e * DIM + (j >> 1) * 128 + wn * 32 + (j & 1) * 16 + lr];

#pragma unroll
  for (int mf = 0; mf < 4; ++mf)
#pragma unroll
    for (int r = 0; r < 4; ++r) {
      int m = wm * 64 + mf * 16 + lg * 4 + r;
      int gi = t0 + m;
      if (gi >= n_e) continue;
      int ent = lists[e * NTOK + gi];
      int t = ent & 0xFFFF;
      float w = (ent & 0x10000) ? 1.0f : 0.5f;
      float* orow = out + (size_t)t * DIM;
#pragma unroll
      for (int j = 0; j < 8; ++j) {
        int col = (j >> 1) * 128 + wn * 32 + (j & 1) * 16 + lr;
        atomicAdd(orow + col, (acc2[mf][j][r] + b2v[j]) * w);
      }
    }
}

extern "C" void kernel_launch(void* const* d_in, const int* in_sizes, int n_in,
                              void* d_out, int out_size, void* d_ws, size_t ws_size,
                              hipStream_t stream) {
  const float* x      = (const float*)d_in[0];
  const int*   assign = (const int*)d_in[1];
  const float* W1     = (const float*)d_in[2];
  const float* b1     = (const float*)d_in[3];
  const float* W2     = (const float*)d_in[4];
  const float* b2     = (const float*)d_in[5];
  float* out = (float*)d_out;

  char* ws = (char*)d_ws;
  int* cnt   = (int*)ws;
  int* lists = (int*)(ws + 1024);
  ushort_t* Xb  = (ushort_t*)(ws + (2ull << 20));        // 33.6 MB
  ushort_t* W1b = (ushort_t*)(ws + 35651584ull);         // 16.8 MB
  ushort_t* W2b = (ushort_t*)(ws + 52428800ull);         // 16.8 MB, ends ~69.2 MB

  (void)hipMemsetAsync(d_out, 0, (size_t)out_size * sizeof(float), stream);
  (void)hipMemsetAsync(cnt, 0, 256, stream);

  moe_route<<<NTOK / 256, 256, 0, stream>>>(assign, cnt, lists);
  cvt_x<<<NTOK * DIM / 4 / 256, 256, 0, stream>>>((const f32x4*)x, (us4*)Xb);
  transp_cvt<<<dim3(HID / 64, DIM / 64, NE), 256, 0, stream>>>(W1, W1b, DIM, HID);
  transp_cvt<<<dim3(DIM / 64, HID / 64, NE), 256, 0, stream>>>(W2, W2b, HID, DIM);

  (void)hipFuncSetAttribute((const void*)moe_gemm,
                            hipFuncAttributeMaxDynamicSharedMemorySize, LDS_BYTES);
  moe_gemm<<<NE * MAXTILE, 512, LDS_BYTES, stream>>>(Xb, W1b, b1, W2b, b2,
                                                     cnt, lists, out);
}

// Round 6
// 659.637 us; speedup vs baseline: 1.8224x; 1.8224x over previous
//
#include <hip/hip_runtime.h>

// MoE: x[8,4096,512]f32, assign[8,4096,2]i32, W1[8,512,2048], b1[8,2048],
//      W2[8,2048,512], b2[8,512] -> out[8,4096,512]f32
// v6: X-RESIDENT fused grouped GEMM. TM=64 tokens/block; X staged once into
//     LDS (64KB) and kept resident; W1/W2 stream through a 2x32KB ring with
//     counted vmcnt(4); H[64][256] bounced in LDS; one barrier per phase.

#define NTOK 32768
#define DIM  512
#define HID  2048
#define NE   8
#define TM   64
#define MAXTILE 128           // 128*64 = 8192 >> n_e (~7680+-85)

#define XBASE 0               // 64 x 512 bf16, row 1024B, 64 units, swz low3
#define HBASE 65536           // 64 x 256 bf16, row 512B, 32 units, swz low3
#define RBASE 98304           // 2 x 32768B ring buffers (rows of 128B, 8 units)
#define LDS_BYTES 163840

typedef __attribute__((ext_vector_type(8))) short short8;
typedef __attribute__((ext_vector_type(4))) float f32x4;
typedef __attribute__((ext_vector_type(4))) unsigned short us4;
typedef unsigned short ushort_t;

__device__ __forceinline__ unsigned short f2bf(float f) {
  union { float f; unsigned u; } v; v.f = f;
  unsigned r = v.u + 0x7FFFu + ((v.u >> 16) & 1u);  // RNE
  return (unsigned short)(r >> 16);
}

__device__ __forceinline__ void g2l16(const void* g, void* l) {
  __builtin_amdgcn_global_load_lds(
      (const __attribute__((address_space(1))) void*)g,
      (__attribute__((address_space(3))) void*)l, 16, 0, 0);
}

// ---------------- routing ----------------
__global__ void moe_route(const int* __restrict__ assign, int* __restrict__ cnt,
                          int* __restrict__ lists) {
  int t = blockIdx.x * blockDim.x + threadIdx.x;
  if (t >= NTOK) return;
  int a0 = assign[2 * t + 0];
  int a1 = assign[2 * t + 1];
  if (a0 == a1) {
    int p = atomicAdd(&cnt[a0], 1);
    lists[a0 * NTOK + p] = t | 0x10000;  // weight 1.0
  } else {
    int p0 = atomicAdd(&cnt[a0], 1);
    lists[a0 * NTOK + p0] = t;           // weight 0.5
    int p1 = atomicAdd(&cnt[a1], 1);
    lists[a1 * NTOK + p1] = t;
  }
}

// ---------------- converters ----------------
__global__ __launch_bounds__(256) void cvt_x(const f32x4* __restrict__ x,
                                             us4* __restrict__ xb) {
  int i = blockIdx.x * 256 + threadIdx.x;
  f32x4 v = __builtin_nontemporal_load(&x[i]);
  us4 p;
  p.x = f2bf(v.x); p.y = f2bf(v.y); p.z = f2bf(v.z); p.w = f2bf(v.w);
  xb[i] = p;
}

// src: [E][R][C] fp32 -> dst: [E][C][R] bf16 (transpose + convert)
__global__ __launch_bounds__(256) void transp_cvt(const float* __restrict__ src,
                                                  ushort_t* __restrict__ dst,
                                                  int R, int C) {
  __shared__ float tile[64][68];
  const int e = blockIdx.z;
  const int rb = blockIdx.y * 64, cb = blockIdx.x * 64;
  const int t = threadIdx.x;
  {
    const int tr = t >> 2, tc = (t & 3) * 16;
    const f32x4* s = (const f32x4*)(src + ((size_t)e * R + rb + tr) * C + cb + tc);
    f32x4 v0 = __builtin_nontemporal_load(s + 0);
    f32x4 v1 = __builtin_nontemporal_load(s + 1);
    f32x4 v2 = __builtin_nontemporal_load(s + 2);
    f32x4 v3 = __builtin_nontemporal_load(s + 3);
    *(f32x4*)&tile[tr][tc + 0]  = v0;
    *(f32x4*)&tile[tr][tc + 4]  = v1;
    *(f32x4*)&tile[tr][tc + 8]  = v2;
    *(f32x4*)&tile[tr][tc + 12] = v3;
  }
  __syncthreads();
  {
    const int n = t >> 2, ks = (t & 3) * 16;
    short8 o0, o1;
#pragma unroll
    for (int j = 0; j < 8; ++j) o0[j] = (short)f2bf(tile[ks + j][n]);
#pragma unroll
    for (int j = 0; j < 8; ++j) o1[j] = (short)f2bf(tile[ks + 8 + j][n]);
    ushort_t* d = dst + ((size_t)e * C + cb + n) * R + rb + ks;
    *(short8*)(d) = o0;
    *(short8*)(d + 8) = o1;
  }
}

// ---------------- fused expert GEMM, X-resident ----------------
__global__ __launch_bounds__(512, 1) void moe_gemm(
    const ushort_t* __restrict__ Xb, const ushort_t* __restrict__ W1b,
    const float* __restrict__ b1, const ushort_t* __restrict__ W2b,
    const float* __restrict__ b2, const int* __restrict__ cnt,
    const int* __restrict__ lists, float* __restrict__ out) {
  extern __shared__ char smem[];

  const int id = blockIdx.x;
  const int e = id & 7;          // expert == XCD (round-robin dispatch)
  const int tile = id >> 3;
  const int n_e = cnt[e];
  const int t0 = tile * TM;
  if (t0 >= n_e) return;

  const int tid = threadIdx.x;
  const int wid = tid >> 6;
  const int lane = tid & 63;
  const int lr = tid & 15, lg = lane >> 4;
  const int lr7 = lr & 7;
  const int l3 = lane >> 3, l7 = lane & 7;   // staging decomposition
  const int wm = wid >> 2;   // G2 m-half
  const int wo = wid & 3;    // G2 out quarter (within 256-half)

  // W streaming helpers: ring buffer rows of 128B (64 bf16), 8 units of 16B,
  // unit pre-swizzled at the global source by row&7 (= l3).
  auto stW1 = [&](int c, int p, int buf) {
#pragma unroll
    for (int i = 0; i < 4; ++i) {
      int j = wid * 4 + i;                        // 0..31 -> rows j*8..+7
      int row = j * 8 + l3;                       // hid row within chunk
      const ushort_t* g = W1b + ((size_t)(e * HID) + c * 256 + row) * DIM +
                          p * 64 + (l7 ^ l3) * 8;
      g2l16(g, smem + RBASE + buf * 32768 + j * 1024 + lane * 16);
    }
  };
  auto stW2 = [&](int c, int oh, int kp, int buf) {
#pragma unroll
    for (int i = 0; i < 4; ++i) {
      int j = wid * 4 + i;
      int row = j * 8 + l3;                       // out row within half
      const ushort_t* g = W2b + ((size_t)(e * DIM) + oh * 256 + row) * HID +
                          c * 256 + kp * 64 + (l7 ^ l3) * 8;
      g2l16(g, smem + RBASE + buf * 32768 + j * 1024 + lane * 16);
    }
  };

  // ---- prologue: b1(chunk0) -> X stage (once) -> W1 piece0 -> buf0 ----
  float b1c0 = b1[e * HID + wid * 32 + lr];
  float b1c1 = b1[e * HID + wid * 32 + 16 + lr];
  __builtin_amdgcn_sched_barrier(0);
  {
    int tk[8];
#pragma unroll
    for (int i = 0; i < 8; ++i) {
      int idx = t0 + wid * 8 + i;
      tk[i] = lists[e * NTOK + (idx < n_e ? idx : 0)] & 0xFFFF;
    }
#pragma unroll
    for (int i = 0; i < 8; ++i) {
      int row = wid * 8 + i;                      // row&7 == i
      int su = (lane & ~7) | (l7 ^ i);
      g2l16(Xb + (size_t)tk[i] * DIM + su * 8,
            smem + XBASE + row * 1024 + lane * 16);
    }
  }
  stW1(0, 0, 0);
  __builtin_amdgcn_sched_barrier(0);

  f32x4 acc2[2][8];
#pragma unroll
  for (int i = 0; i < 2; ++i)
#pragma unroll
    for (int j = 0; j < 8; ++j) acc2[i][j] = f32x4{0.f, 0.f, 0.f, 0.f};

  for (int c = 0; c < 8; ++c) {
    const int cn = (c + 1) & 7;
    float b1n0 = 0.f, b1n1 = 0.f;

    f32x4 acc1[4][2];
#pragma unroll
    for (int i = 0; i < 4; ++i) {
      acc1[i][0] = f32x4{0.f, 0.f, 0.f, 0.f};
      acc1[i][1] = f32x4{0.f, 0.f, 0.f, 0.f};
    }

    // ===== G1: acc1 = X[64x512] @ W1[:, c*256:+256] (8 phases of 64k) =====
#pragma unroll
    for (int p = 0; p < 8; ++p) {
      if (p < 7) stW1(c, p + 1, (p + 1) & 1);
      else       stW2(c, 0, 0, 0);
      __builtin_amdgcn_sched_barrier(0);
      asm volatile("s_waitcnt vmcnt(4)" ::: "memory");
      __builtin_amdgcn_sched_barrier(0);
      __builtin_amdgcn_s_barrier();
      __builtin_amdgcn_sched_barrier(0);

      const char* bufp = smem + RBASE + (p & 1) * 32768;
#pragma unroll
      for (int kf = 0; kf < 2; ++kf) {
        short8 av[4], bv[2];
#pragma unroll
        for (int mf = 0; mf < 4; ++mf) {
          int row = mf * 16 + lr;
          int u = p * 8 + kf * 4 + lg;            // 0..63
          av[mf] = *(const short8*)(smem + XBASE + row * 1024 +
                                    (((u & ~7) | ((u & 7) ^ lr7))) * 16);
        }
#pragma unroll
        for (int nf = 0; nf < 2; ++nf) {
          int row = wid * 32 + nf * 16 + lr;      // hid row 0..255
          int u = kf * 4 + lg;                    // 0..7
          bv[nf] = *(const short8*)(bufp + row * 128 + ((u ^ lr7)) * 16);
        }
        __builtin_amdgcn_s_setprio(1);
#pragma unroll
        for (int mf = 0; mf < 4; ++mf)
#pragma unroll
          for (int nf = 0; nf < 2; ++nf)
            acc1[mf][nf] = __builtin_amdgcn_mfma_f32_16x16x32_bf16(
                av[mf], bv[nf], acc1[mf][nf], 0, 0, 0);
        __builtin_amdgcn_s_setprio(0);
      }
      if (p == 7) {  // bias + relu -> H (swizzled bf16 [64][256])
#pragma unroll
        for (int mf = 0; mf < 4; ++mf)
#pragma unroll
          for (int nf = 0; nf < 2; ++nf)
#pragma unroll
            for (int r = 0; r < 4; ++r) {
              int wrow = mf * 16 + lg * 4 + r;
              int col = wid * 32 + nf * 16 + lr;
              float hv = fmaxf(acc1[mf][nf][r] + (nf ? b1c1 : b1c0), 0.0f);
              int u = col >> 3;                   // 0..31
              *(ushort_t*)(smem + HBASE + wrow * 512 +
                           (((u & ~7) | ((u & 7) ^ (wrow & 7)))) * 16 +
                           (col & 7) * 2) = f2bf(hv);
            }
        __builtin_amdgcn_sched_barrier(0);
        asm volatile("s_waitcnt lgkmcnt(0)" ::: "memory");
        __builtin_amdgcn_sched_barrier(0);
      }
    }

    // ===== G2: acc2 += H[64x256] @ W2chunk (8 phases: oh=q>>2, kp=q&3) =====
#pragma unroll
    for (int q = 0; q < 8; ++q) {
      if (q == 0) {
        b1n0 = b1[e * HID + cn * 256 + wid * 32 + lr];
        b1n1 = b1[e * HID + cn * 256 + wid * 32 + 16 + lr];
        __builtin_amdgcn_sched_barrier(0);
      }
      if (q < 7) stW2(c, (q + 1) >> 2, (q + 1) & 3, (q + 1) & 1);
      else       stW1(cn, 0, 0);
      __builtin_amdgcn_sched_barrier(0);
      asm volatile("s_waitcnt vmcnt(4)" ::: "memory");
      __builtin_amdgcn_sched_barrier(0);
      __builtin_amdgcn_s_barrier();
      __builtin_amdgcn_sched_barrier(0);

      const int oh = q >> 2, kp = q & 3;
      const char* bufp = smem + RBASE + (q & 1) * 32768;
#pragma unroll
      for (int kf = 0; kf < 2; ++kf) {
        short8 a2[2], bw[4];
#pragma unroll
        for (int mf = 0; mf < 2; ++mf) {
          int row = wm * 32 + mf * 16 + lr;
          int u = kp * 8 + kf * 4 + lg;           // 0..31
          a2[mf] = *(const short8*)(smem + HBASE + row * 512 +
                                    (((u & ~7) | ((u & 7) ^ lr7))) * 16);
        }
#pragma unroll
        for (int nf = 0; nf < 4; ++nf) {
          int row = wo * 64 + nf * 16 + lr;       // out row within half
          int u = kf * 4 + lg;
          bw[nf] = *(const short8*)(bufp + row * 128 + ((u ^ lr7)) * 16);
        }
        __builtin_amdgcn_s_setprio(1);
#pragma unroll
        for (int mf = 0; mf < 2; ++mf)
#pragma unroll
          for (int nf = 0; nf < 4; ++nf)
            acc2[mf][oh * 4 + nf] = __builtin_amdgcn_mfma_f32_16x16x32_bf16(
                a2[mf], bw[nf], acc2[mf][oh * 4 + nf], 0, 0, 0);
        __builtin_amdgcn_s_setprio(0);
      }
    }
    b1c0 = b1n0; b1c1 = b1n1;
  }
  asm volatile("" :: "v"(b1c0), "v"(b1c1));  // keep tail prefetch alive

  // ---- epilogue: out[tok] += (acc2 + b2) * w ----
#pragma unroll
  for (int mf = 0; mf < 2; ++mf)
#pragma unroll
    for (int r = 0; r < 4; ++r) {
      int m = wm * 32 + mf * 16 + lg * 4 + r;
      int gi = t0 + m;
      if (gi >= n_e) continue;
      int ent = lists[e * NTOK + gi];
      int t = ent & 0xFFFF;
      float w = (ent & 0x10000) ? 1.0f : 0.5f;
      float* orow = out + (size_t)t * DIM;
#pragma unroll
      for (int oh = 0; oh < 2; ++oh)
#pragma unroll
        for (int nf = 0; nf < 4; ++nf) {
          int col = oh * 256 + wo * 64 + nf * 16 + lr;
          atomicAdd(orow + col, (acc2[mf][oh * 4 + nf][r] + b2[e * DIM + col]) * w);
        }
    }
}

extern "C" void kernel_launch(void* const* d_in, const int* in_sizes, int n_in,
                              void* d_out, int out_size, void* d_ws, size_t ws_size,
                              hipStream_t stream) {
  const float* x      = (const float*)d_in[0];
  const int*   assign = (const int*)d_in[1];
  const float* W1     = (const float*)d_in[2];
  const float* b1     = (const float*)d_in[3];
  const float* W2     = (const float*)d_in[4];
  const float* b2     = (const float*)d_in[5];
  float* out = (float*)d_out;

  char* ws = (char*)d_ws;
  int* cnt   = (int*)ws;
  int* lists = (int*)(ws + 1024);
  ushort_t* Xb  = (ushort_t*)(ws + (2ull << 20));        // 33.6 MB
  ushort_t* W1b = (ushort_t*)(ws + 35651584ull);         // 16.8 MB
  ushort_t* W2b = (ushort_t*)(ws + 52428800ull);         // 16.8 MB, ends ~69.2 MB

  (void)hipMemsetAsync(d_out, 0, (size_t)out_size * sizeof(float), stream);
  (void)hipMemsetAsync(cnt, 0, 256, stream);

  moe_route<<<NTOK / 256, 256, 0, stream>>>(assign, cnt, lists);
  cvt_x<<<NTOK * DIM / 4 / 256, 256, 0, stream>>>((const f32x4*)x, (us4*)Xb);
  transp_cvt<<<dim3(HID / 64, DIM / 64, NE), 256, 0, stream>>>(W1, W1b, DIM, HID);
  transp_cvt<<<dim3(DIM / 64, HID / 64, NE), 256, 0, stream>>>(W2, W2b, HID, DIM);

  (void)hipFuncSetAttribute((const void*)moe_gemm,
                            hipFuncAttributeMaxDynamicSharedMemorySize, LDS_BYTES);
  moe_gemm<<<NE * MAXTILE, 512, LDS_BYTES, stream>>>(Xb, W1b, b1, W2b, b2,
                                                     cnt, lists, out);
}